// Round 20
// baseline (1054.752 us; speedup 1.0000x reference)
//
#include <hip/hip_runtime.h>
#include <stdint.h>

typedef unsigned short u16;
typedef unsigned int u32;
typedef unsigned long long u64;

#define NB 16
#define NP 4096
#define NCH 64
#define NS 1024
#define NK 32
#define H1D 128
#define H2D 256
#define KP1 96
#define LDA 104
#define LDH 136
#define OUTOFF (NB * NS * H2D) /* 4194304 */
#define NCONS 112
#define NGRP 2048 /* 16 clouds x 128 groups of 8 centroids */

typedef __attribute__((ext_vector_type(8))) short bfrag;
typedef __attribute__((ext_vector_type(4))) float facc4;
typedef __attribute__((ext_vector_type(2))) float f32x2;

__device__ __forceinline__ u16 f2bf(float f) {
  u32 u = __float_as_uint(f);
  u += 0x7FFFu + ((u >> 16) & 1u);
  return (u16)(u >> 16);
}

// Exactly replicates jnp.sum((a-b)**2, axis=-1): ((dx*dx+dy*dy)+dz*dz), no fma.
__device__ __forceinline__ float dist2(float ax, float ay, float az,
                                       float bx, float by, float bz) {
#pragma clang fp contract(off)
  float dx = ax - bx, dy = ay - by, dz = az - bz;
  return dx * dx + dy * dy + dz * dz;
}

__device__ __forceinline__ f32x2 dist2v(f32x2 ax, f32x2 ay, f32x2 az,
                                        float bx, float by, float bz) {
#pragma clang fp contract(off)
  f32x2 dx = ax - bx, dy = ay - by, dz = az - bz;
  return dx * dx + dy * dy + dz * dz;
}

__device__ __forceinline__ float wave_max_f32(float v) {
  const int NI = (int)0xFF800000u;
  v = fmaxf(v, __int_as_float(__builtin_amdgcn_update_dpp(NI, __float_as_int(v), 0x111, 0xf, 0xf, false)));
  v = fmaxf(v, __int_as_float(__builtin_amdgcn_update_dpp(NI, __float_as_int(v), 0x112, 0xf, 0xf, false)));
  v = fmaxf(v, __int_as_float(__builtin_amdgcn_update_dpp(NI, __float_as_int(v), 0x114, 0xf, 0xf, false)));
  v = fmaxf(v, __int_as_float(__builtin_amdgcn_update_dpp(NI, __float_as_int(v), 0x118, 0xf, 0xf, false)));
  v = fmaxf(v, __int_as_float(__builtin_amdgcn_update_dpp(NI, __float_as_int(v), 0x142, 0xa, 0xf, false)));
  v = fmaxf(v, __int_as_float(__builtin_amdgcn_update_dpp(NI, __float_as_int(v), 0x143, 0xc, 0xf, false)));
  return __int_as_float(__builtin_amdgcn_readlane(__float_as_int(v), 63));
}

__device__ __forceinline__ u32 wave_min_u32(u32 v) {
  u32 t;
  t = (u32)__builtin_amdgcn_update_dpp(-1, (int)v, 0x111, 0xf, 0xf, false); v = t < v ? t : v;
  t = (u32)__builtin_amdgcn_update_dpp(-1, (int)v, 0x112, 0xf, 0xf, false); v = t < v ? t : v;
  t = (u32)__builtin_amdgcn_update_dpp(-1, (int)v, 0x114, 0xf, 0xf, false); v = t < v ? t : v;
  t = (u32)__builtin_amdgcn_update_dpp(-1, (int)v, 0x118, 0xf, 0xf, false); v = t < v ? t : v;
  t = (u32)__builtin_amdgcn_update_dpp(-1, (int)v, 0x142, 0xa, 0xf, false); v = t < v ? t : v;
  t = (u32)__builtin_amdgcn_update_dpp(-1, (int)v, 0x143, 0xc, 0xf, false); v = t < v ? t : v;
  return (u32)__builtin_amdgcn_readlane((int)v, 63);
}

// 4-slot quad_perm butterfly carrying (key, x, y, z).
#define QUAD_MAX_STEP(CTRL)                                                           \
  {                                                                                   \
    const u32 plo = (u32)__builtin_amdgcn_update_dpp(0, (int)klo, (CTRL), 0xf, 0xf, true); \
    const u32 phi = (u32)__builtin_amdgcn_update_dpp(0, (int)khi, (CTRL), 0xf, 0xf, true); \
    const u32 pqx = (u32)__builtin_amdgcn_update_dpp(0, (int)qxu, (CTRL), 0xf, 0xf, true); \
    const u32 pqy = (u32)__builtin_amdgcn_update_dpp(0, (int)qyu, (CTRL), 0xf, 0xf, true); \
    const u32 pqz = (u32)__builtin_amdgcn_update_dpp(0, (int)qzu, (CTRL), 0xf, 0xf, true); \
    const u64 ok = ((u64)phi << 32) | plo;                                            \
    const u64 mk = ((u64)khi << 32) | klo;                                            \
    if (ok > mk) { klo = plo; khi = phi; qxu = pqx; qyu = pqy; qzu = pqz; }           \
  }

// ---------------- K0: transpose + pad + bf16-convert weights ----------------
__global__ void setup_kernel(const float* __restrict__ W1, const float* __restrict__ W2,
                             u16* __restrict__ W1T, u16* __restrict__ W2T) {
  int idx = blockIdx.x * 256 + threadIdx.x;
  if (idx < H1D * KP1) {
    int n = idx / KP1, k = idx % KP1;
    W1T[idx] = f2bf(k < 67 ? W1[k * H1D + n] : 0.f);
  } else if (idx < H1D * KP1 + H2D * H1D) {
    int j = idx - H1D * KP1;
    int n = j / H1D, k = j % H1D;
    W2T[j] = f2bf(W2[k * H2D + n]);
  }
}

// ---------------- Fused producer/consumer kernel ----------------
// r19 form (755us) with ONE change: NCONS 176 -> 112 (grid 128, half the CUs).
// The isolated NCONS test (r18->r19: 240->176, fused 800->779) confirmed the
// co-residency/clock-headroom effect; this continues the same knob. Capacity:
// steady-state demand = 2.6 groups/us x 15us = ~39 busy consumers << 112;
// readiness monotone in G; last 16 groups on 16 distinct consumers (tail
// unchanged). Publication byte-identical to r16/r18/r19: wave 4 lane 0,
// 16 sc1-relaxed stores + prog RELEASE every 16 iters (no explicit fence).
__global__ __launch_bounds__(512) void fused_kernel(
    const float* __restrict__ x, const float* __restrict__ pos,
    const float* __restrict__ b1, const float* __restrict__ b2,
    const u16* __restrict__ W1T, const u16* __restrict__ W2T,
    int* __restrict__ samp, u32* __restrict__ prog, float* __restrict__ out) {
  __shared__ __align__(16) unsigned char smem[123936];
  const int tid = threadIdx.x;
  const int lane = tid & 63, w = tid >> 6;

  if (blockIdx.x < 16) {
    // ================= producer: FPS for cloud b =================
    float4* plds = (float4*)smem;            // 64 KiB
    u32* recs = (u32*)(smem + 65536);        // [2][4][8] u32
    u16* gilist = (u16*)(smem + 65792);      // 2 KiB
    float* pos_s = out + OUTOFF;
    const int b = blockIdx.x;
    const float* pb = pos + (size_t)b * NP * 3;
    for (int k = tid; k < NP; k += 512)
      plds[k] = make_float4(pb[k * 3 + 0], pb[k * 3 + 1], pb[k * 3 + 2], 0.f);
    if (tid == 0) gilist[0] = 0;
    __syncthreads();

    f32x2 px2[8], py2[8], pz2[8], dd[8];
    float bv = -1.f;
    int bj = 0;
    if (tid < 256) {
      const float4 q0 = plds[0];
#pragma unroll
      for (int t = 0; t < 8; ++t) {
        const float4 pA = plds[tid * 16 + 2 * t];
        const float4 pB = plds[tid * 16 + 2 * t + 1];
        px2[t] = (f32x2){pA.x, pB.x};
        py2[t] = (f32x2){pA.y, pB.y};
        pz2[t] = (f32x2){pA.z, pB.z};
        const f32x2 s = dist2v(px2[t], py2[t], pz2[t], q0.x, q0.y, q0.z);
        dd[t] = s;
        // ascending p = tid*16 + 2t(+1); strict > => first occurrence
        const bool c0 = s.x > bv; bv = c0 ? s.x : bv; bj = c0 ? 2 * t : bj;
        const bool c1 = s.y > bv; bv = c1 ? s.y : bv; bj = c1 ? 2 * t + 1 : bj;
      }
    }

    for (int i = 1; i < NS; ++i) {
      if (tid < 256) {
        const int gidx = tid * 16 + bj;
        const float4 cpos = plds[gidx];  // speculative; hides under DPP chain
        const float wmax = wave_max_f32(bv);
        const u64 mask = __ballot(bv == wmax);
        const bool winner = (bv == wmax) && ((mask & ((1ull << lane) - 1ull)) == 0ull);
        if (winner) {
          u32* rp = &recs[(((i & 1) << 2) + w) * 8];
          *(uint4*)rp = make_uint4(4095u - (u32)gidx, __float_as_uint(bv),
                                   __float_as_uint(cpos.x), __float_as_uint(cpos.y));
          rp[4] = __float_as_uint(cpos.z);
        }
      }
      __syncthreads();  // LDS-only drain for waves 0-3 (no global ops in loop)
      if (tid < 256) {
        const u32* sp = &recs[(((i & 1) << 2) + (lane & 3)) * 8];
        const uint4 rA = *(const uint4*)sp;
        u32 klo = rA.x, khi = rA.y, qxu = rA.z, qyu = rA.w, qzu = sp[4];
        QUAD_MAX_STEP(0xB1)
        QUAD_MAX_STEP(0x4E)
        const float qx = __uint_as_float(qxu);
        const float qy = __uint_as_float(qyu);
        const float qz = __uint_as_float(qzu);
        if (tid == 0) gilist[i] = (u16)(4095 - (int)(klo & 0xFFFu));  // LDS only
        bv = -1.f; bj = 0;
#pragma unroll
        for (int t = 0; t < 8; ++t) {
          const f32x2 s = dist2v(px2[t], py2[t], pz2[t], qx, qy, qz);
          dd[t].x = fminf(dd[t].x, s.x);
          dd[t].y = fminf(dd[t].y, s.y);
          const bool c0 = dd[t].x > bv; bv = c0 ? dd[t].x : bv; bj = c0 ? 2 * t : bj;
          const bool c1 = dd[t].y > bv; bv = c1 ? dd[t].y : bv; bj = c1 ? 2 * t + 1 : bj;
        }
      } else if (w == 4 && lane == 0 && i >= 16 && (i & 15) == 0) {
        // publish batch [i-16, i): gilist entries were all written before the
        // barrier of this iteration. Same-thread relaxed sc1 data stores then
        // RELEASE flag = message-passing pattern, batched; the ~600-900cy ack
        // hides in the 1575cy iteration (wave 4 is otherwise idle).
#pragma unroll
        for (int k = 0; k < 16; ++k)
          __hip_atomic_store(&samp[b * NS + (i - 16) + k], (int)gilist[(i - 16) + k],
                             __ATOMIC_RELAXED, __HIP_MEMORY_SCOPE_AGENT);
        __hip_atomic_store(&prog[b], (u32)i, __ATOMIC_RELEASE,
                           __HIP_MEMORY_SCOPE_AGENT);
      }
    }
    __syncthreads();
    if (w == 4 && lane == 0) {
      for (int k = 1008; k < NS; ++k)
        __hip_atomic_store(&samp[b * NS + k], (int)gilist[k], __ATOMIC_RELAXED,
                           __HIP_MEMORY_SCOPE_AGENT);
      __hip_atomic_store(&prog[b], (u32)NS, __ATOMIC_RELEASE,
                         __HIP_MEMORY_SCOPE_AGENT);
    }
    // deferred pos_s writeback (host-read only; plain stores fine)
    for (int k = tid; k < NS; k += 512) {
      const int gi = (int)gilist[k];
      const float4 q = plds[gi];
      pos_s[((size_t)b * NS + k) * 3 + 0] = q.x;
      pos_s[((size_t)b * NS + k) * 3 + 1] = q.y;
      pos_s[((size_t)b * NS + k) * 3 + 2] = q.z;
    }
  } else {
    // ================= consumer: ballq + MLP for groups of 8 =================
    u64* qbuf = (u64*)smem;                    // [8][256] during ballq
    u16* A = (u16*)smem;                       // 256 x LDA bf16 (overlays qbuf)
    u16* Hs = (u16*)(smem + 53248);            // 256 x LDH bf16
    int* s_nbr = (int*)(smem + 122880);        // [8][32]
    int* s_nc = (int*)(smem + 123904);         // [8]
    const int r16 = lane & 15, g4 = lane >> 4;
    for (int G = (int)blockIdx.x - 16; G < NGRP; G += NCONS) {
      const int b = G & 15;
      const int i0 = (G >> 4) << 3;
      if (tid == 0) {
        const u32 need = (u32)(i0 + 8);
        while (__hip_atomic_load(&prog[b], __ATOMIC_ACQUIRE,
                                 __HIP_MEMORY_SCOPE_AGENT) < need)
          __builtin_amdgcn_s_sleep(32);
      }
      __syncthreads();
      // agent-scope loads: bypass this XCD's (possibly stale) caches
      if (tid < 8)
        s_nc[tid] = __hip_atomic_load(&samp[b * NS + i0 + tid], __ATOMIC_RELAXED,
                                      __HIP_MEMORY_SCOPE_AGENT);
      __syncthreads();
      const float* pb = pos + (size_t)b * NP * 3;
      {  // ---- ballq: wave w -> centroid i0+w ----
        const int nc = s_nc[w];
        const float cx = pb[nc * 3 + 0], cy = pb[nc * 3 + 1], cz = pb[nc * 3 + 2];
        const float r2 = (float)(0.2 * 0.2);
        u64* qb = qbuf + (size_t)w * 256;
        int V = 0;
        for (int c = 0; c < 64; ++c) {
          const int i = c * 64 + lane;
          const float d2v = dist2(cx, cy, cz, pb[i * 3 + 0], pb[i * 3 + 1], pb[i * 3 + 2]);
          const bool valid = d2v <= r2;
          const u64 bal = __ballot(valid);
          if (valid) {
            const int rank = __popcll(bal & ((1ull << lane) - 1ull));
            const int p = V + rank;
            if (p < 256) qb[p] = ((u64)__float_as_uint(d2v) << 32) | (u32)i;
          }
          V += __popcll(bal);
        }
        if (V > 256) V = 256;  // P ~ 1e-21 (mean 137, sd 11.5)
        u32 kd[4], ki[4];
#pragma unroll
        for (int t = 0; t < 4; ++t) {
          const int p = t * 64 + lane;
          const u64 v = (p < V) ? qb[p] : ~0ull;
          kd[t] = (u32)(v >> 32);
          ki[t] = (u32)v;
        }
        u32 my = 0, pad = 0;
        for (int e = 0; e < 32; ++e) {
          u32 m0 = kd[0] < kd[1] ? kd[0] : kd[1];
          u32 m1 = kd[2] < kd[3] ? kd[2] : kd[3];
          const u32 m = wave_min_u32(m0 < m1 ? m0 : m1);
          u32 ci = 0xFFFFFFFFu;
#pragma unroll
          for (int t = 0; t < 4; ++t) {
            const u32 cm = (ki[t] < ci) ? ki[t] : ci;
            ci = (kd[t] == m) ? cm : ci;
          }
          const u32 wi = wave_min_u32(ci);
          if (e == 0) pad = wi;
          const u32 sel = (m == 0xFFFFFFFFu) ? pad : wi;
          if (lane == e) my = sel;
#pragma unroll
          for (int t = 0; t < 4; ++t)
            if (ki[t] == wi) kd[t] = 0xFFFFFFFFu;
        }
        if (lane < 32) s_nbr[w * 32 + lane] = (int)my;
      }
      __syncthreads();  // qbuf dead; A may overlay it
      {  // ---- stage A tile: 256 rows x 96 cols bf16 (x | rel | zeros) ----
        const int row = tid >> 1, half = tid & 1;
        const int n = s_nbr[(row >> 5) * 32 + (row & 31)];
        const float4* xr = (const float4*)(x + ((size_t)b * NP + n) * NCH + half * 32);
#pragma unroll
        for (int qq = 0; qq < 4; ++qq) {
          const float4 v0 = xr[2 * qq], v1 = xr[2 * qq + 1];
          uint4 wp;
          wp.x = (u32)f2bf(v0.x) | ((u32)f2bf(v0.y) << 16);
          wp.y = (u32)f2bf(v0.z) | ((u32)f2bf(v0.w) << 16);
          wp.z = (u32)f2bf(v1.x) | ((u32)f2bf(v1.y) << 16);
          wp.w = (u32)f2bf(v1.z) | ((u32)f2bf(v1.w) << 16);
          *(uint4*)&A[row * LDA + half * 32 + qq * 8] = wp;
        }
        if (half == 0) {
          const int ncg = s_nc[row >> 5];
          // bit-identical to pos_j - pos_s (pos_s is a bit-copy of pos rows)
          const float rx = pb[n * 3 + 0] - pb[ncg * 3 + 0];
          const float ry = pb[n * 3 + 1] - pb[ncg * 3 + 1];
          const float rz = pb[n * 3 + 2] - pb[ncg * 3 + 2];
          uint4 wr;
          wr.x = (u32)f2bf(rx) | ((u32)f2bf(ry) << 16);
          wr.y = (u32)f2bf(rz);
          wr.z = 0; wr.w = 0;
          uint4 wz; wz.x = wz.y = wz.z = wz.w = 0;
          *(uint4*)&A[row * LDA + 64] = wr;
          *(uint4*)&A[row * LDA + 72] = wz;
          *(uint4*)&A[row * LDA + 80] = wz;
          *(uint4*)&A[row * LDA + 88] = wz;
        }
      }
      __syncthreads();
      {  // ---- layer 1 (swapped operands): lane l holds m=l&15, n=g4*4+r ----
        bfrag af[2][3];
#pragma unroll
        for (int mg2 = 0; mg2 < 2; ++mg2)
#pragma unroll
          for (int ks = 0; ks < 3; ++ks)
            af[mg2][ks] = *(const bfrag*)&A[((2 * w + mg2) * 16 + r16) * LDA + ks * 32 + g4 * 8];
#pragma unroll
        for (int ng = 0; ng < 8; ++ng) {
          const bfrag bw0 = *(const bfrag*)&W1T[(ng * 16 + r16) * KP1 + 0 + g4 * 8];
          const bfrag bw1 = *(const bfrag*)&W1T[(ng * 16 + r16) * KP1 + 32 + g4 * 8];
          const bfrag bw2 = *(const bfrag*)&W1T[(ng * 16 + r16) * KP1 + 64 + g4 * 8];
          facc4 a0 = {0.f, 0.f, 0.f, 0.f}, a1 = {0.f, 0.f, 0.f, 0.f};
          a0 = __builtin_amdgcn_mfma_f32_16x16x32_bf16(bw0, af[0][0], a0, 0, 0, 0);
          a0 = __builtin_amdgcn_mfma_f32_16x16x32_bf16(bw1, af[0][1], a0, 0, 0, 0);
          a0 = __builtin_amdgcn_mfma_f32_16x16x32_bf16(bw2, af[0][2], a0, 0, 0, 0);
          a1 = __builtin_amdgcn_mfma_f32_16x16x32_bf16(bw0, af[1][0], a1, 0, 0, 0);
          a1 = __builtin_amdgcn_mfma_f32_16x16x32_bf16(bw1, af[1][1], a1, 0, 0, 0);
          a1 = __builtin_amdgcn_mfma_f32_16x16x32_bf16(bw2, af[1][2], a1, 0, 0, 0);
          const float4 bias4 = *(const float4*)&b1[ng * 16 + g4 * 4];
          const int nb = ng * 16 + g4 * 4;
          u32 lo0 = (u32)f2bf(fmaxf(a0[0] + bias4.x, 0.f)) | ((u32)f2bf(fmaxf(a0[1] + bias4.y, 0.f)) << 16);
          u32 hi0 = (u32)f2bf(fmaxf(a0[2] + bias4.z, 0.f)) | ((u32)f2bf(fmaxf(a0[3] + bias4.w, 0.f)) << 16);
          u32 lo1 = (u32)f2bf(fmaxf(a1[0] + bias4.x, 0.f)) | ((u32)f2bf(fmaxf(a1[1] + bias4.y, 0.f)) << 16);
          u32 hi1 = (u32)f2bf(fmaxf(a1[2] + bias4.z, 0.f)) | ((u32)f2bf(fmaxf(a1[3] + bias4.w, 0.f)) << 16);
          *(uint2*)&Hs[((2 * w + 0) * 16 + r16) * LDH + nb] = make_uint2(lo0, hi0);
          *(uint2*)&Hs[((2 * w + 1) * 16 + r16) * LDH + nb] = make_uint2(lo1, hi1);
        }
      }
      __syncthreads();
      {  // ---- layer 2 + maxpool: wave w owns centroid i0+w ----
        bfrag hf[2][4];
#pragma unroll
        for (int mg2 = 0; mg2 < 2; ++mg2)
#pragma unroll
          for (int ks = 0; ks < 4; ++ks)
            hf[mg2][ks] = *(const bfrag*)&Hs[((2 * w + mg2) * 16 + r16) * LDH + ks * 32 + g4 * 8];
        const size_t gout = (size_t)(b * NS + i0 + w);
        const int NI = (int)0xFF800000u;
#pragma unroll
        for (int ng = 0; ng < 16; ++ng) {
          facc4 a0 = {0.f, 0.f, 0.f, 0.f}, a1 = {0.f, 0.f, 0.f, 0.f};
#pragma unroll
          for (int ks = 0; ks < 4; ++ks) {
            const bfrag bw = *(const bfrag*)&W2T[(ng * 16 + r16) * H1D + ks * 32 + g4 * 8];
            a0 = __builtin_amdgcn_mfma_f32_16x16x32_bf16(bw, hf[0][ks], a0, 0, 0, 0);
            a1 = __builtin_amdgcn_mfma_f32_16x16x32_bf16(bw, hf[1][ks], a1, 0, 0, 0);
          }
          float v0 = fmaxf(a0[0], a1[0]);
          float v1 = fmaxf(a0[1], a1[1]);
          float v2 = fmaxf(a0[2], a1[2]);
          float v3 = fmaxf(a0[3], a1[3]);
          v0 = fmaxf(v0, __int_as_float(__builtin_amdgcn_update_dpp(NI, __float_as_int(v0), 0x111, 0xf, 0xf, false)));
          v1 = fmaxf(v1, __int_as_float(__builtin_amdgcn_update_dpp(NI, __float_as_int(v1), 0x111, 0xf, 0xf, false)));
          v2 = fmaxf(v2, __int_as_float(__builtin_amdgcn_update_dpp(NI, __float_as_int(v2), 0x111, 0xf, 0xf, false)));
          v3 = fmaxf(v3, __int_as_float(__builtin_amdgcn_update_dpp(NI, __float_as_int(v3), 0x111, 0xf, 0xf, false)));
          v0 = fmaxf(v0, __int_as_float(__builtin_amdgcn_update_dpp(NI, __float_as_int(v0), 0x112, 0xf, 0xf, false)));
          v1 = fmaxf(v1, __int_as_float(__builtin_amdgcn_update_dpp(NI, __float_as_int(v1), 0x112, 0xf, 0xf, false)));
          v2 = fmaxf(v2, __int_as_float(__builtin_amdgcn_update_dpp(NI, __float_as_int(v2), 0x112, 0xf, 0xf, false)));
          v3 = fmaxf(v3, __int_as_float(__builtin_amdgcn_update_dpp(NI, __float_as_int(v3), 0x112, 0xf, 0xf, false)));
          v0 = fmaxf(v0, __int_as_float(__builtin_amdgcn_update_dpp(NI, __float_as_int(v0), 0x114, 0xf, 0xf, false)));
          v1 = fmaxf(v1, __int_as_float(__builtin_amdgcn_update_dpp(NI, __float_as_int(v1), 0x114, 0xf, 0xf, false)));
          v2 = fmaxf(v2, __int_as_float(__builtin_amdgcn_update_dpp(NI, __float_as_int(v2), 0x114, 0xf, 0xf, false)));
          v3 = fmaxf(v3, __int_as_float(__builtin_amdgcn_update_dpp(NI, __float_as_int(v3), 0x114, 0xf, 0xf, false)));
          v0 = fmaxf(v0, __int_as_float(__builtin_amdgcn_update_dpp(NI, __float_as_int(v0), 0x118, 0xf, 0xf, false)));
          v1 = fmaxf(v1, __int_as_float(__builtin_amdgcn_update_dpp(NI, __float_as_int(v1), 0x118, 0xf, 0xf, false)));
          v2 = fmaxf(v2, __int_as_float(__builtin_amdgcn_update_dpp(NI, __float_as_int(v2), 0x118, 0xf, 0xf, false)));
          v3 = fmaxf(v3, __int_as_float(__builtin_amdgcn_update_dpp(NI, __float_as_int(v3), 0x118, 0xf, 0xf, false)));
          if ((lane & 15) == 15) {
            const float4 b24 = *(const float4*)&b2[ng * 16 + g4 * 4];
            float4 o;
            o.x = fmaxf(v0 + b24.x, 0.f);
            o.y = fmaxf(v1 + b24.y, 0.f);
            o.z = fmaxf(v2 + b24.z, 0.f);
            o.w = fmaxf(v3 + b24.w, 0.f);
            *(float4*)&out[gout * H2D + ng * 16 + g4 * 4] = o;
          }
        }
      }
      __syncthreads();  // protect A/Hs/qbuf/s_nbr/s_nc reuse next group
    }
  }
}

extern "C" void kernel_launch(void* const* d_in, const int* in_sizes, int n_in,
                              void* d_out, int out_size, void* d_ws, size_t ws_size,
                              hipStream_t stream) {
  const float* x = (const float*)d_in[0];
  const float* pos = (const float*)d_in[1];
  const float* W1 = (const float*)d_in[2];
  const float* b1 = (const float*)d_in[3];
  const float* W2 = (const float*)d_in[4];
  const float* b2 = (const float*)d_in[5];
  float* out = (float*)d_out;
  char* ws = (char*)d_ws;
  u16* W1T = (u16*)(ws + 0);        // 24576 B
  u16* W2T = (u16*)(ws + 24576);    // 65536 B
  int* samp = (int*)(ws + 90112);   // 65536 B
  u32* prog = (u32*)(ws + 155648);  // 64 B, re-zeroed every call below

  hipMemsetAsync(ws + 155648, 0, 64, stream);
  setup_kernel<<<dim3(176), dim3(256), 0, stream>>>(W1, W2, W1T, W2T);
  fused_kernel<<<dim3(16 + NCONS), dim3(512), 0, stream>>>(x, pos, b1, b2, W1T, W2T,
                                                           samp, prog, out);
}

// Round 21
// 753.656 us; speedup vs baseline: 1.3995x; 1.3995x over previous
//
#include <hip/hip_runtime.h>
#include <stdint.h>

typedef unsigned short u16;
typedef unsigned int u32;
typedef unsigned long long u64;

#define NB 16
#define NP 4096
#define NCH 64
#define NS 1024
#define NK 32
#define H1D 128
#define H2D 256
#define KP1 96
#define LDA 104
#define LDH 136
#define OUTOFF (NB * NS * H2D) /* 4194304 */
#define NCONS 176
#define NGRP 2048 /* 16 clouds x 128 groups of 8 centroids */

typedef __attribute__((ext_vector_type(8))) short bfrag;
typedef __attribute__((ext_vector_type(4))) float facc4;
typedef __attribute__((ext_vector_type(2))) float f32x2;

__device__ __forceinline__ u16 f2bf(float f) {
  u32 u = __float_as_uint(f);
  u += 0x7FFFu + ((u >> 16) & 1u);
  return (u16)(u >> 16);
}

// Exactly replicates jnp.sum((a-b)**2, axis=-1): ((dx*dx+dy*dy)+dz*dz), no fma.
__device__ __forceinline__ float dist2(float ax, float ay, float az,
                                       float bx, float by, float bz) {
#pragma clang fp contract(off)
  float dx = ax - bx, dy = ay - by, dz = az - bz;
  return dx * dx + dy * dy + dz * dz;
}

__device__ __forceinline__ f32x2 dist2v(f32x2 ax, f32x2 ay, f32x2 az,
                                        float bx, float by, float bz) {
#pragma clang fp contract(off)
  f32x2 dx = ax - bx, dy = ay - by, dz = az - bz;
  return dx * dx + dy * dy + dz * dz;
}

__device__ __forceinline__ float wave_max_f32(float v) {
  const int NI = (int)0xFF800000u;
  v = fmaxf(v, __int_as_float(__builtin_amdgcn_update_dpp(NI, __float_as_int(v), 0x111, 0xf, 0xf, false)));
  v = fmaxf(v, __int_as_float(__builtin_amdgcn_update_dpp(NI, __float_as_int(v), 0x112, 0xf, 0xf, false)));
  v = fmaxf(v, __int_as_float(__builtin_amdgcn_update_dpp(NI, __float_as_int(v), 0x114, 0xf, 0xf, false)));
  v = fmaxf(v, __int_as_float(__builtin_amdgcn_update_dpp(NI, __float_as_int(v), 0x118, 0xf, 0xf, false)));
  v = fmaxf(v, __int_as_float(__builtin_amdgcn_update_dpp(NI, __float_as_int(v), 0x142, 0xa, 0xf, false)));
  v = fmaxf(v, __int_as_float(__builtin_amdgcn_update_dpp(NI, __float_as_int(v), 0x143, 0xc, 0xf, false)));
  return __int_as_float(__builtin_amdgcn_readlane(__float_as_int(v), 63));
}

__device__ __forceinline__ u32 wave_min_u32(u32 v) {
  u32 t;
  t = (u32)__builtin_amdgcn_update_dpp(-1, (int)v, 0x111, 0xf, 0xf, false); v = t < v ? t : v;
  t = (u32)__builtin_amdgcn_update_dpp(-1, (int)v, 0x112, 0xf, 0xf, false); v = t < v ? t : v;
  t = (u32)__builtin_amdgcn_update_dpp(-1, (int)v, 0x114, 0xf, 0xf, false); v = t < v ? t : v;
  t = (u32)__builtin_amdgcn_update_dpp(-1, (int)v, 0x118, 0xf, 0xf, false); v = t < v ? t : v;
  t = (u32)__builtin_amdgcn_update_dpp(-1, (int)v, 0x142, 0xa, 0xf, false); v = t < v ? t : v;
  t = (u32)__builtin_amdgcn_update_dpp(-1, (int)v, 0x143, 0xc, 0xf, false); v = t < v ? t : v;
  return (u32)__builtin_amdgcn_readlane((int)v, 63);
}

// 4-slot quad_perm butterfly carrying (key, x, y, z).
#define QUAD_MAX_STEP(CTRL)                                                           \
  {                                                                                   \
    const u32 plo = (u32)__builtin_amdgcn_update_dpp(0, (int)klo, (CTRL), 0xf, 0xf, true); \
    const u32 phi = (u32)__builtin_amdgcn_update_dpp(0, (int)khi, (CTRL), 0xf, 0xf, true); \
    const u32 pqx = (u32)__builtin_amdgcn_update_dpp(0, (int)qxu, (CTRL), 0xf, 0xf, true); \
    const u32 pqy = (u32)__builtin_amdgcn_update_dpp(0, (int)qyu, (CTRL), 0xf, 0xf, true); \
    const u32 pqz = (u32)__builtin_amdgcn_update_dpp(0, (int)qzu, (CTRL), 0xf, 0xf, true); \
    const u64 ok = ((u64)phi << 32) | plo;                                            \
    const u64 mk = ((u64)khi << 32) | klo;                                            \
    if (ok > mk) { klo = plo; khi = phi; qxu = pqx; qyu = pqy; qzu = pqz; }           \
  }

// ---------------- K0: transpose + pad + bf16-convert weights ----------------
__global__ void setup_kernel(const float* __restrict__ W1, const float* __restrict__ W2,
                             u16* __restrict__ W1T, u16* __restrict__ W2T) {
  int idx = blockIdx.x * 256 + threadIdx.x;
  if (idx < H1D * KP1) {
    int n = idx / KP1, k = idx % KP1;
    W1T[idx] = f2bf(k < 67 ? W1[k * H1D + n] : 0.f);
  } else if (idx < H1D * KP1 + H2D * H1D) {
    int j = idx - H1D * KP1;
    int n = j / H1D, k = j % H1D;
    W2T[j] = f2bf(W2[k * H2D + n]);
  }
}

// ---------------- Fused producer/consumer kernel (round-19 form, best 755us) ----
// Grid 192 x 512, 123.9 KB LDS -> 1 block/CU. Blocks 0-15: FPS producers
// (waves 0-3 compute with ZERO global ops in-loop; winner indices -> LDS
// gilist; wave 4 lane 0 publishes batches of 16 samp entries sc1-relaxed +
// prog RELEASE every 16 iters). Blocks 16-191: 176 consumers (ACQUIRE prog
// spin -> sc1 samp loads -> ballq 8 centroids -> 256-row MFMA MLP), the whole
// tail hidden under the producer. NCONS bracketing: 112 -> consumer-bound
// (~1078); 176 -> hidden + min co-residency drag (755); 240 -> +12us drag.
// Producers never wait on consumers -> no deadlock.
__global__ __launch_bounds__(512) void fused_kernel(
    const float* __restrict__ x, const float* __restrict__ pos,
    const float* __restrict__ b1, const float* __restrict__ b2,
    const u16* __restrict__ W1T, const u16* __restrict__ W2T,
    int* __restrict__ samp, u32* __restrict__ prog, float* __restrict__ out) {
  __shared__ __align__(16) unsigned char smem[123936];
  const int tid = threadIdx.x;
  const int lane = tid & 63, w = tid >> 6;

  if (blockIdx.x < 16) {
    // ================= producer: FPS for cloud b =================
    float4* plds = (float4*)smem;            // 64 KiB
    u32* recs = (u32*)(smem + 65536);        // [2][4][8] u32
    u16* gilist = (u16*)(smem + 65792);      // 2 KiB
    float* pos_s = out + OUTOFF;
    const int b = blockIdx.x;
    const float* pb = pos + (size_t)b * NP * 3;
    for (int k = tid; k < NP; k += 512)
      plds[k] = make_float4(pb[k * 3 + 0], pb[k * 3 + 1], pb[k * 3 + 2], 0.f);
    if (tid == 0) gilist[0] = 0;
    __syncthreads();

    f32x2 px2[8], py2[8], pz2[8], dd[8];
    float bv = -1.f;
    int bj = 0;
    if (tid < 256) {
      const float4 q0 = plds[0];
#pragma unroll
      for (int t = 0; t < 8; ++t) {
        const float4 pA = plds[tid * 16 + 2 * t];
        const float4 pB = plds[tid * 16 + 2 * t + 1];
        px2[t] = (f32x2){pA.x, pB.x};
        py2[t] = (f32x2){pA.y, pB.y};
        pz2[t] = (f32x2){pA.z, pB.z};
        const f32x2 s = dist2v(px2[t], py2[t], pz2[t], q0.x, q0.y, q0.z);
        dd[t] = s;
        // ascending p = tid*16 + 2t(+1); strict > => first occurrence
        const bool c0 = s.x > bv; bv = c0 ? s.x : bv; bj = c0 ? 2 * t : bj;
        const bool c1 = s.y > bv; bv = c1 ? s.y : bv; bj = c1 ? 2 * t + 1 : bj;
      }
    }

    for (int i = 1; i < NS; ++i) {
      if (tid < 256) {
        const int gidx = tid * 16 + bj;
        const float4 cpos = plds[gidx];  // speculative; hides under DPP chain
        const float wmax = wave_max_f32(bv);
        const u64 mask = __ballot(bv == wmax);
        const bool winner = (bv == wmax) && ((mask & ((1ull << lane) - 1ull)) == 0ull);
        if (winner) {
          u32* rp = &recs[(((i & 1) << 2) + w) * 8];
          *(uint4*)rp = make_uint4(4095u - (u32)gidx, __float_as_uint(bv),
                                   __float_as_uint(cpos.x), __float_as_uint(cpos.y));
          rp[4] = __float_as_uint(cpos.z);
        }
      }
      __syncthreads();  // LDS-only drain for waves 0-3 (no global ops in loop)
      if (tid < 256) {
        const u32* sp = &recs[(((i & 1) << 2) + (lane & 3)) * 8];
        const uint4 rA = *(const uint4*)sp;
        u32 klo = rA.x, khi = rA.y, qxu = rA.z, qyu = rA.w, qzu = sp[4];
        QUAD_MAX_STEP(0xB1)
        QUAD_MAX_STEP(0x4E)
        const float qx = __uint_as_float(qxu);
        const float qy = __uint_as_float(qyu);
        const float qz = __uint_as_float(qzu);
        if (tid == 0) gilist[i] = (u16)(4095 - (int)(klo & 0xFFFu));  // LDS only
        bv = -1.f; bj = 0;
#pragma unroll
        for (int t = 0; t < 8; ++t) {
          const f32x2 s = dist2v(px2[t], py2[t], pz2[t], qx, qy, qz);
          dd[t].x = fminf(dd[t].x, s.x);
          dd[t].y = fminf(dd[t].y, s.y);
          const bool c0 = dd[t].x > bv; bv = c0 ? dd[t].x : bv; bj = c0 ? 2 * t : bj;
          const bool c1 = dd[t].y > bv; bv = c1 ? dd[t].y : bv; bj = c1 ? 2 * t + 1 : bj;
        }
      } else if (w == 4 && lane == 0 && i >= 16 && (i & 15) == 0) {
        // publish batch [i-16, i): gilist entries were all written before the
        // barrier of this iteration. Same-thread relaxed sc1 data stores then
        // RELEASE flag = message-passing pattern, batched; the ~600-900cy ack
        // hides in the 1575cy iteration (wave 4 is otherwise idle).
#pragma unroll
        for (int k = 0; k < 16; ++k)
          __hip_atomic_store(&samp[b * NS + (i - 16) + k], (int)gilist[(i - 16) + k],
                             __ATOMIC_RELAXED, __HIP_MEMORY_SCOPE_AGENT);
        __hip_atomic_store(&prog[b], (u32)i, __ATOMIC_RELEASE,
                           __HIP_MEMORY_SCOPE_AGENT);
      }
    }
    __syncthreads();
    if (w == 4 && lane == 0) {
      for (int k = 1008; k < NS; ++k)
        __hip_atomic_store(&samp[b * NS + k], (int)gilist[k], __ATOMIC_RELAXED,
                           __HIP_MEMORY_SCOPE_AGENT);
      __hip_atomic_store(&prog[b], (u32)NS, __ATOMIC_RELEASE,
                         __HIP_MEMORY_SCOPE_AGENT);
    }
    // deferred pos_s writeback (host-read only; plain stores fine)
    for (int k = tid; k < NS; k += 512) {
      const int gi = (int)gilist[k];
      const float4 q = plds[gi];
      pos_s[((size_t)b * NS + k) * 3 + 0] = q.x;
      pos_s[((size_t)b * NS + k) * 3 + 1] = q.y;
      pos_s[((size_t)b * NS + k) * 3 + 2] = q.z;
    }
  } else {
    // ================= consumer: ballq + MLP for groups of 8 =================
    u64* qbuf = (u64*)smem;                    // [8][256] during ballq
    u16* A = (u16*)smem;                       // 256 x LDA bf16 (overlays qbuf)
    u16* Hs = (u16*)(smem + 53248);            // 256 x LDH bf16
    int* s_nbr = (int*)(smem + 122880);        // [8][32]
    int* s_nc = (int*)(smem + 123904);         // [8]
    const int r16 = lane & 15, g4 = lane >> 4;
    for (int G = (int)blockIdx.x - 16; G < NGRP; G += NCONS) {
      const int b = G & 15;
      const int i0 = (G >> 4) << 3;
      if (tid == 0) {
        const u32 need = (u32)(i0 + 8);
        while (__hip_atomic_load(&prog[b], __ATOMIC_ACQUIRE,
                                 __HIP_MEMORY_SCOPE_AGENT) < need)
          __builtin_amdgcn_s_sleep(32);
      }
      __syncthreads();
      // agent-scope loads: bypass this XCD's (possibly stale) caches
      if (tid < 8)
        s_nc[tid] = __hip_atomic_load(&samp[b * NS + i0 + tid], __ATOMIC_RELAXED,
                                      __HIP_MEMORY_SCOPE_AGENT);
      __syncthreads();
      const float* pb = pos + (size_t)b * NP * 3;
      {  // ---- ballq: wave w -> centroid i0+w ----
        const int nc = s_nc[w];
        const float cx = pb[nc * 3 + 0], cy = pb[nc * 3 + 1], cz = pb[nc * 3 + 2];
        const float r2 = (float)(0.2 * 0.2);
        u64* qb = qbuf + (size_t)w * 256;
        int V = 0;
        for (int c = 0; c < 64; ++c) {
          const int i = c * 64 + lane;
          const float d2v = dist2(cx, cy, cz, pb[i * 3 + 0], pb[i * 3 + 1], pb[i * 3 + 2]);
          const bool valid = d2v <= r2;
          const u64 bal = __ballot(valid);
          if (valid) {
            const int rank = __popcll(bal & ((1ull << lane) - 1ull));
            const int p = V + rank;
            if (p < 256) qb[p] = ((u64)__float_as_uint(d2v) << 32) | (u32)i;
          }
          V += __popcll(bal);
        }
        if (V > 256) V = 256;  // P ~ 1e-21 (mean 137, sd 11.5)
        u32 kd[4], ki[4];
#pragma unroll
        for (int t = 0; t < 4; ++t) {
          const int p = t * 64 + lane;
          const u64 v = (p < V) ? qb[p] : ~0ull;
          kd[t] = (u32)(v >> 32);
          ki[t] = (u32)v;
        }
        u32 my = 0, pad = 0;
        for (int e = 0; e < 32; ++e) {
          u32 m0 = kd[0] < kd[1] ? kd[0] : kd[1];
          u32 m1 = kd[2] < kd[3] ? kd[2] : kd[3];
          const u32 m = wave_min_u32(m0 < m1 ? m0 : m1);
          u32 ci = 0xFFFFFFFFu;
#pragma unroll
          for (int t = 0; t < 4; ++t) {
            const u32 cm = (ki[t] < ci) ? ki[t] : ci;
            ci = (kd[t] == m) ? cm : ci;
          }
          const u32 wi = wave_min_u32(ci);
          if (e == 0) pad = wi;
          const u32 sel = (m == 0xFFFFFFFFu) ? pad : wi;
          if (lane == e) my = sel;
#pragma unroll
          for (int t = 0; t < 4; ++t)
            if (ki[t] == wi) kd[t] = 0xFFFFFFFFu;
        }
        if (lane < 32) s_nbr[w * 32 + lane] = (int)my;
      }
      __syncthreads();  // qbuf dead; A may overlay it
      {  // ---- stage A tile: 256 rows x 96 cols bf16 (x | rel | zeros) ----
        const int row = tid >> 1, half = tid & 1;
        const int n = s_nbr[(row >> 5) * 32 + (row & 31)];
        const float4* xr = (const float4*)(x + ((size_t)b * NP + n) * NCH + half * 32);
#pragma unroll
        for (int qq = 0; qq < 4; ++qq) {
          const float4 v0 = xr[2 * qq], v1 = xr[2 * qq + 1];
          uint4 wp;
          wp.x = (u32)f2bf(v0.x) | ((u32)f2bf(v0.y) << 16);
          wp.y = (u32)f2bf(v0.z) | ((u32)f2bf(v0.w) << 16);
          wp.z = (u32)f2bf(v1.x) | ((u32)f2bf(v1.y) << 16);
          wp.w = (u32)f2bf(v1.z) | ((u32)f2bf(v1.w) << 16);
          *(uint4*)&A[row * LDA + half * 32 + qq * 8] = wp;
        }
        if (half == 0) {
          const int ncg = s_nc[row >> 5];
          // bit-identical to pos_j - pos_s (pos_s is a bit-copy of pos rows)
          const float rx = pb[n * 3 + 0] - pb[ncg * 3 + 0];
          const float ry = pb[n * 3 + 1] - pb[ncg * 3 + 1];
          const float rz = pb[n * 3 + 2] - pb[ncg * 3 + 2];
          uint4 wr;
          wr.x = (u32)f2bf(rx) | ((u32)f2bf(ry) << 16);
          wr.y = (u32)f2bf(rz);
          wr.z = 0; wr.w = 0;
          uint4 wz; wz.x = wz.y = wz.z = wz.w = 0;
          *(uint4*)&A[row * LDA + 64] = wr;
          *(uint4*)&A[row * LDA + 72] = wz;
          *(uint4*)&A[row * LDA + 80] = wz;
          *(uint4*)&A[row * LDA + 88] = wz;
        }
      }
      __syncthreads();
      {  // ---- layer 1 (swapped operands): lane l holds m=l&15, n=g4*4+r ----
        bfrag af[2][3];
#pragma unroll
        for (int mg2 = 0; mg2 < 2; ++mg2)
#pragma unroll
          for (int ks = 0; ks < 3; ++ks)
            af[mg2][ks] = *(const bfrag*)&A[((2 * w + mg2) * 16 + r16) * LDA + ks * 32 + g4 * 8];
#pragma unroll
        for (int ng = 0; ng < 8; ++ng) {
          const bfrag bw0 = *(const bfrag*)&W1T[(ng * 16 + r16) * KP1 + 0 + g4 * 8];
          const bfrag bw1 = *(const bfrag*)&W1T[(ng * 16 + r16) * KP1 + 32 + g4 * 8];
          const bfrag bw2 = *(const bfrag*)&W1T[(ng * 16 + r16) * KP1 + 64 + g4 * 8];
          facc4 a0 = {0.f, 0.f, 0.f, 0.f}, a1 = {0.f, 0.f, 0.f, 0.f};
          a0 = __builtin_amdgcn_mfma_f32_16x16x32_bf16(bw0, af[0][0], a0, 0, 0, 0);
          a0 = __builtin_amdgcn_mfma_f32_16x16x32_bf16(bw1, af[0][1], a0, 0, 0, 0);
          a0 = __builtin_amdgcn_mfma_f32_16x16x32_bf16(bw2, af[0][2], a0, 0, 0, 0);
          a1 = __builtin_amdgcn_mfma_f32_16x16x32_bf16(bw0, af[1][0], a1, 0, 0, 0);
          a1 = __builtin_amdgcn_mfma_f32_16x16x32_bf16(bw1, af[1][1], a1, 0, 0, 0);
          a1 = __builtin_amdgcn_mfma_f32_16x16x32_bf16(bw2, af[1][2], a1, 0, 0, 0);
          const float4 bias4 = *(const float4*)&b1[ng * 16 + g4 * 4];
          const int nb = ng * 16 + g4 * 4;
          u32 lo0 = (u32)f2bf(fmaxf(a0[0] + bias4.x, 0.f)) | ((u32)f2bf(fmaxf(a0[1] + bias4.y, 0.f)) << 16);
          u32 hi0 = (u32)f2bf(fmaxf(a0[2] + bias4.z, 0.f)) | ((u32)f2bf(fmaxf(a0[3] + bias4.w, 0.f)) << 16);
          u32 lo1 = (u32)f2bf(fmaxf(a1[0] + bias4.x, 0.f)) | ((u32)f2bf(fmaxf(a1[1] + bias4.y, 0.f)) << 16);
          u32 hi1 = (u32)f2bf(fmaxf(a1[2] + bias4.z, 0.f)) | ((u32)f2bf(fmaxf(a1[3] + bias4.w, 0.f)) << 16);
          *(uint2*)&Hs[((2 * w + 0) * 16 + r16) * LDH + nb] = make_uint2(lo0, hi0);
          *(uint2*)&Hs[((2 * w + 1) * 16 + r16) * LDH + nb] = make_uint2(lo1, hi1);
        }
      }
      __syncthreads();
      {  // ---- layer 2 + maxpool: wave w owns centroid i0+w ----
        bfrag hf[2][4];
#pragma unroll
        for (int mg2 = 0; mg2 < 2; ++mg2)
#pragma unroll
          for (int ks = 0; ks < 4; ++ks)
            hf[mg2][ks] = *(const bfrag*)&Hs[((2 * w + mg2) * 16 + r16) * LDH + ks * 32 + g4 * 8];
        const size_t gout = (size_t)(b * NS + i0 + w);
        const int NI = (int)0xFF800000u;
#pragma unroll
        for (int ng = 0; ng < 16; ++ng) {
          facc4 a0 = {0.f, 0.f, 0.f, 0.f}, a1 = {0.f, 0.f, 0.f, 0.f};
#pragma unroll
          for (int ks = 0; ks < 4; ++ks) {
            const bfrag bw = *(const bfrag*)&W2T[(ng * 16 + r16) * H1D + ks * 32 + g4 * 8];
            a0 = __builtin_amdgcn_mfma_f32_16x16x32_bf16(bw, hf[0][ks], a0, 0, 0, 0);
            a1 = __builtin_amdgcn_mfma_f32_16x16x32_bf16(bw, hf[1][ks], a1, 0, 0, 0);
          }
          float v0 = fmaxf(a0[0], a1[0]);
          float v1 = fmaxf(a0[1], a1[1]);
          float v2 = fmaxf(a0[2], a1[2]);
          float v3 = fmaxf(a0[3], a1[3]);
          v0 = fmaxf(v0, __int_as_float(__builtin_amdgcn_update_dpp(NI, __float_as_int(v0), 0x111, 0xf, 0xf, false)));
          v1 = fmaxf(v1, __int_as_float(__builtin_amdgcn_update_dpp(NI, __float_as_int(v1), 0x111, 0xf, 0xf, false)));
          v2 = fmaxf(v2, __int_as_float(__builtin_amdgcn_update_dpp(NI, __float_as_int(v2), 0x111, 0xf, 0xf, false)));
          v3 = fmaxf(v3, __int_as_float(__builtin_amdgcn_update_dpp(NI, __float_as_int(v3), 0x111, 0xf, 0xf, false)));
          v0 = fmaxf(v0, __int_as_float(__builtin_amdgcn_update_dpp(NI, __float_as_int(v0), 0x112, 0xf, 0xf, false)));
          v1 = fmaxf(v1, __int_as_float(__builtin_amdgcn_update_dpp(NI, __float_as_int(v1), 0x112, 0xf, 0xf, false)));
          v2 = fmaxf(v2, __int_as_float(__builtin_amdgcn_update_dpp(NI, __float_as_int(v2), 0x112, 0xf, 0xf, false)));
          v3 = fmaxf(v3, __int_as_float(__builtin_amdgcn_update_dpp(NI, __float_as_int(v3), 0x112, 0xf, 0xf, false)));
          v0 = fmaxf(v0, __int_as_float(__builtin_amdgcn_update_dpp(NI, __float_as_int(v0), 0x114, 0xf, 0xf, false)));
          v1 = fmaxf(v1, __int_as_float(__builtin_amdgcn_update_dpp(NI, __float_as_int(v1), 0x114, 0xf, 0xf, false)));
          v2 = fmaxf(v2, __int_as_float(__builtin_amdgcn_update_dpp(NI, __float_as_int(v2), 0x114, 0xf, 0xf, false)));
          v3 = fmaxf(v3, __int_as_float(__builtin_amdgcn_update_dpp(NI, __float_as_int(v3), 0x114, 0xf, 0xf, false)));
          v0 = fmaxf(v0, __int_as_float(__builtin_amdgcn_update_dpp(NI, __float_as_int(v0), 0x118, 0xf, 0xf, false)));
          v1 = fmaxf(v1, __int_as_float(__builtin_amdgcn_update_dpp(NI, __float_as_int(v1), 0x118, 0xf, 0xf, false)));
          v2 = fmaxf(v2, __int_as_float(__builtin_amdgcn_update_dpp(NI, __float_as_int(v2), 0x118, 0xf, 0xf, false)));
          v3 = fmaxf(v3, __int_as_float(__builtin_amdgcn_update_dpp(NI, __float_as_int(v3), 0x118, 0xf, 0xf, false)));
          if ((lane & 15) == 15) {
            const float4 b24 = *(const float4*)&b2[ng * 16 + g4 * 4];
            float4 o;
            o.x = fmaxf(v0 + b24.x, 0.f);
            o.y = fmaxf(v1 + b24.y, 0.f);
            o.z = fmaxf(v2 + b24.z, 0.f);
            o.w = fmaxf(v3 + b24.w, 0.f);
            *(float4*)&out[gout * H2D + ng * 16 + g4 * 4] = o;
          }
        }
      }
      __syncthreads();  // protect A/Hs/qbuf/s_nbr/s_nc reuse next group
    }
  }
}

extern "C" void kernel_launch(void* const* d_in, const int* in_sizes, int n_in,
                              void* d_out, int out_size, void* d_ws, size_t ws_size,
                              hipStream_t stream) {
  const float* x = (const float*)d_in[0];
  const float* pos = (const float*)d_in[1];
  const float* W1 = (const float*)d_in[2];
  const float* b1 = (const float*)d_in[3];
  const float* W2 = (const float*)d_in[4];
  const float* b2 = (const float*)d_in[5];
  float* out = (float*)d_out;
  char* ws = (char*)d_ws;
  u16* W1T = (u16*)(ws + 0);        // 24576 B
  u16* W2T = (u16*)(ws + 24576);    // 65536 B
  int* samp = (int*)(ws + 90112);   // 65536 B
  u32* prog = (u32*)(ws + 155648);  // 64 B, re-zeroed every call below

  hipMemsetAsync(ws + 155648, 0, 64, stream);
  setup_kernel<<<dim3(176), dim3(256), 0, stream>>>(W1, W2, W1T, W2T);
  fused_kernel<<<dim3(16 + NCONS), dim3(512), 0, stream>>>(x, pos, b1, b2, W1T, W2T,
                                                           samp, prog, out);
}